// Round 10
// baseline (402.901 us; speedup 1.0000x reference)
//
#include <hip/hip_runtime.h>

#define BB 8
#define CC 192
#define C3 576
#define HW 16384
#define HEADS 4
#define CHD 48
#define NPLANE (BB*CC)

typedef short s8v __attribute__((ext_vector_type(8)));
typedef float f16v __attribute__((ext_vector_type(16)));
typedef float f4v __attribute__((ext_vector_type(4)));

__device__ __forceinline__ ushort bfu(float f) {
    union { float f; unsigned u; } c; c.f = f;
    unsigned u = c.u + 0x7FFFu + ((c.u >> 16) & 1u);
    return (ushort)(u >> 16);
}
__device__ __forceinline__ float ubf(ushort u) {
    union { unsigned u; float f; } c; c.u = ((unsigned)u) << 16;
    return c.f;
}

// ---- transpose to MFMA-B layout: x [b][c][p] fp32 -> T [b][c/8][p][8c] bf16
// Also folds in: w_qkv -> wPack conversion (blocks y==1,z==0) and G zeroing (y==0,z==0).
__global__ __launch_bounds__(256) void k_trans(
    const float* __restrict__ xf, ushort* __restrict__ T,
    const float* __restrict__ wq, ushort* __restrict__ wbf, float* __restrict__ G)
{
    const int b = blockIdx.x, cg = blockIdx.y;
    const int p = blockIdx.z * 1024 + threadIdx.x * 4;
    if (blockIdx.z == 0) {
        if (cg == 0) {          // zero G: 73728 f over 8 blocks
            float4 z = {0.f, 0.f, 0.f, 0.f};
            int base = b * 9216 + threadIdx.x * 4;
            #pragma unroll
            for (int i = 0; i < 9; i++) *(float4*)(G + base + i * 1024) = z;
        } else if (cg == 1) {   // w_qkv fp32 [576][192] -> bf16 A-frag order
            int base = b * 13824;
            #pragma unroll 2
            for (int i = 0; i < 54; i++) {
                int idx = base + i * 256 + threadIdx.x;
                int o = idx / CC, k = idx % CC;
                int sec = o / CC;
                int ol = o - sec * CC;
                wbf[(size_t)sec * CC * CC + (size_t)(k >> 3) * CC * 8 + ol * 8 + (k & 7)] = bfu(wq[idx]);
            }
        }
    }
    float a[8][4];
    #pragma unroll
    for (int c = 0; c < 8; c++)
        *(float4*)a[c] = *(const float4*)(xf + ((size_t)(b * CC + cg * 8 + c) * HW + p));
    #pragma unroll
    for (int j = 0; j < 4; j++) {
        unsigned wp[4];
        #pragma unroll
        for (int i = 0; i < 4; i++)
            wp[i] = (unsigned)bfu(a[2*i][j]) | ((unsigned)bfu(a[2*i+1][j]) << 16);
        *(uint4*)(T + ((size_t)(b * 24 + cg) * HW + p + j) * 8) = *(const uint4*)wp;
    }
}

__device__ __forceinline__ void loadk(int ks, const ushort* Ab, const ushort* Bb,
    int kg, int wr, int wc, int ll, int pbase, s8v a[3], s8v b[2])
{
    #pragma unroll
    for (int mt = 0; mt < 3; mt++)
        a[mt] = *(const s8v*)(Ab + ((size_t)(ks * 2 + kg) * CC + wr * 96 + mt * 32 + ll) * 8);
    #pragma unroll
    for (int nt = 0; nt < 2; nt++)
        b[nt] = *(const s8v*)(Bb + ((size_t)(ks * 2 + kg) * HW + pbase + wc * 64 + nt * 32 + ll) * 8);
}

// ---- MFMA GEMM: reg ping-pong K-loop, per-wave LDS repack epilogue (no barriers).
// MODE0: A=wPack (3 sections) -> q,k planes (d_out) + v planes; MODE1: A=MPack[b] -> fp32 out.
template<int MODE>
__global__ __launch_bounds__(256) void gemm_mfma(
    const ushort* __restrict__ A,
    const ushort* __restrict__ BT,
    ushort* __restrict__ qk, ushort* __restrict__ vpl,
    float* __restrict__ outf)
{
    __shared__ ushort RepU[MODE == 0 ? 4 * 32 * 40 : 4];   // per-wave ushort[32][40]
    __shared__ float  RepF[MODE == 1 ? 4 * 32 * 36 : 4];   // per-wave float[32][36]
    int lin = blockIdx.x, sec, pt, b;
    if (MODE == 0) {
        int logical = (lin & 7) * 384 + (lin >> 3);   // XCD-contiguous (3072/8=384)
        sec = logical % 3;
        int pb = logical / 3;
        pt = pb & 127; b = pb >> 7;
    } else {
        int logical = (lin & 7) * 128 + (lin >> 3);   // each XCD owns one batch
        sec = 0; b = logical >> 7; pt = logical & 127;
    }
    const int t = threadIdx.x, lane = t & 63, w = t >> 6;
    const int wr = w >> 1, wc = w & 1;
    const int ll = lane & 31, kg = lane >> 5;
    const int pbase = pt * 128;
    const ushort* Ab = A + (size_t)(MODE == 0 ? sec : b) * CC * CC;
    const ushort* Bb = BT + (size_t)b * 24 * HW * 8;

    f16v acc[3][2];
    #pragma unroll
    for (int mt = 0; mt < 3; mt++)
        #pragma unroll
        for (int nt = 0; nt < 2; nt++)
            #pragma unroll
            for (int i = 0; i < 16; i++) acc[mt][nt][i] = 0.f;

    s8v a0[3], b0[2], a1[3], b1[2];
    loadk(0, Ab, Bb, kg, wr, wc, ll, pbase, a0, b0);
    #pragma unroll
    for (int kk = 0; kk < 6; kk++) {
        loadk(2 * kk + 1, Ab, Bb, kg, wr, wc, ll, pbase, a1, b1);
        #pragma unroll
        for (int mt = 0; mt < 3; mt++)
            #pragma unroll
            for (int nt = 0; nt < 2; nt++)
                acc[mt][nt] = __builtin_amdgcn_mfma_f32_32x32x16_bf16(a0[mt], b0[nt], acc[mt][nt], 0, 0, 0);
        if (kk < 5) loadk(2 * kk + 2, Ab, Bb, kg, wr, wc, ll, pbase, a0, b0);
        #pragma unroll
        for (int mt = 0; mt < 3; mt++)
            #pragma unroll
            for (int nt = 0; nt < 2; nt++)
                acc[mt][nt] = __builtin_amdgcn_mfma_f32_32x32x16_bf16(a1[mt], b1[nt], acc[mt][nt], 0, 0, 0);
    }

    if (MODE == 0) {
        ushort* patch = RepU + w * (32 * 40);
        ushort* ob = (sec == 2) ? vpl + (size_t)b * CC * HW
                                : qk + (size_t)(sec * BB + b) * CC * HW;
        #pragma unroll
        for (int mt = 0; mt < 3; mt++)
            #pragma unroll
            for (int nt = 0; nt < 2; nt++) {
                #pragma unroll
                for (int g = 0; g < 4; g++)
                    #pragma unroll
                    for (int j = 0; j < 4; j++)
                        patch[(j + 8 * g + 4 * kg) * 40 + ll] = bfu(acc[mt][nt][4 * g + j]);
                #pragma unroll
                for (int i = 0; i < 2; i++) {
                    int c = lane + 64 * i;
                    int ol = c >> 2, p8 = (c & 3) * 8;
                    int4 v = *(const int4*)&patch[ol * 40 + p8];
                    int o = wr * 96 + mt * 32 + ol;
                    *(int4*)(ob + (size_t)o * HW + pbase + wc * 64 + nt * 32 + p8) = v;
                }
            }
    } else {
        float* patch = RepF + w * (32 * 36);
        #pragma unroll
        for (int mt = 0; mt < 3; mt++)
            #pragma unroll
            for (int nt = 0; nt < 2; nt++) {
                #pragma unroll
                for (int g = 0; g < 4; g++)
                    #pragma unroll
                    for (int j = 0; j < 4; j++)
                        patch[(j + 8 * g + 4 * kg) * 36 + ll] = acc[mt][nt][4 * g + j];
                #pragma unroll
                for (int i = 0; i < 4; i++) {
                    int c = lane + 64 * i;
                    int ol = c >> 3, p4 = (c & 7) * 4;
                    float4 v = *(const float4*)&patch[ol * 36 + p4];
                    int o = wr * 96 + mt * 32 + ol;
                    *(float4*)(outf + ((size_t)b * CC + o) * HW + pbase + wc * 64 + nt * 32 + p4) = v;
                }
            }
    }
}

// ---- in-place depthwise 3x3 on q/k bf16 planes + exact fp32 sum-of-squares.
// 16-row chunks, 18-row LDS ring, cvt_pk output pack.
__global__ __launch_bounds__(256) void k_dw_bf(
    ushort* __restrict__ qk,
    const float* __restrict__ wdw, float* __restrict__ sq, float* __restrict__ sk)
{
    __shared__ ushort rows[18][128];
    __shared__ float red[4];
    int pid = blockIdx.x;
    int sec = pid / NPLANE, rem = pid % NPLANE;
    int b = rem / CC, c = rem % CC;
    ushort* p = qk + ((size_t)(sec * BB + b) * CC + c) * HW;
    const float* wc9 = wdw + (size_t)(sec * CC + c) * 9;
    float w0=wc9[0],w1=wc9[1],w2=wc9[2],w3=wc9[3],w4=wc9[4],w5=wc9[5],w6=wc9[6],w7=wc9[7],w8=wc9[8];
    const int t = threadIdx.x, lr = t >> 5, lx = (t & 31) * 4;
    float ss = 0.f;
    if (t < 32) ((ushort4*)rows[0])[t] = ((const ushort4*)p)[t];
    __syncthreads();
    for (int y0 = 0; y0 < 128; y0 += 16) {
        int ry1 = y0 + 1 + lr, ry2 = y0 + 9 + lr;
        if (ry1 < 128) *(ushort4*)&rows[ry1 % 18][lx] = *(const ushort4*)(p + (size_t)ry1 * 128 + lx);
        if (ry2 < 128) *(ushort4*)&rows[ry2 % 18][lx] = *(const ushort4*)(p + (size_t)ry2 * 128 + lx);
        __syncthreads();
        uint2 outv[2];
        #pragma unroll
        for (int half = 0; half < 2; half++) {
            const int oy = y0 + half * 8 + lr;
            float a0=0,a1=0,a2=0,a3=0;
            if (oy >= 1) {
                const ushort* rw = rows[(oy - 1) % 18];
                float m0=ubf(rw[lx]),m1=ubf(rw[lx+1]),m2=ubf(rw[lx+2]),m3=ubf(rw[lx+3]);
                float lf = lx ? ubf(rw[lx-1]) : 0.f, rt = (lx < 124) ? ubf(rw[lx+4]) : 0.f;
                a0 += w0*lf + w1*m0 + w2*m1;  a1 += w0*m0 + w1*m1 + w2*m2;
                a2 += w0*m1 + w1*m2 + w2*m3;  a3 += w0*m2 + w1*m3 + w2*rt;
            }
            {
                const ushort* rw = rows[oy % 18];
                float m0=ubf(rw[lx]),m1=ubf(rw[lx+1]),m2=ubf(rw[lx+2]),m3=ubf(rw[lx+3]);
                float lf = lx ? ubf(rw[lx-1]) : 0.f, rt = (lx < 124) ? ubf(rw[lx+4]) : 0.f;
                a0 += w3*lf + w4*m0 + w5*m1;  a1 += w3*m0 + w4*m1 + w5*m2;
                a2 += w3*m1 + w4*m2 + w5*m3;  a3 += w3*m2 + w4*m3 + w5*rt;
            }
            if (oy + 1 < 128) {
                const ushort* rw = rows[(oy + 1) % 18];
                float m0=ubf(rw[lx]),m1=ubf(rw[lx+1]),m2=ubf(rw[lx+2]),m3=ubf(rw[lx+3]);
                float lf = lx ? ubf(rw[lx-1]) : 0.f, rt = (lx < 124) ? ubf(rw[lx+4]) : 0.f;
                a0 += w6*lf + w7*m0 + w8*m1;  a1 += w6*m0 + w7*m1 + w8*m2;
                a2 += w6*m1 + w7*m2 + w8*m3;  a3 += w6*m2 + w7*m3 + w8*rt;
            }
            ss += a0*a0 + a1*a1 + a2*a2 + a3*a3;
            unsigned r01, r23;
            asm("v_cvt_pk_bf16_f32 %0, %1, %2" : "=v"(r01) : "v"(a0), "v"(a1));
            asm("v_cvt_pk_bf16_f32 %0, %1, %2" : "=v"(r23) : "v"(a2), "v"(a3));
            outv[half].x = r01; outv[half].y = r23;
        }
        __syncthreads();   // ring reads done before in-place stores / next loads
        *(uint2*)(p + (size_t)(y0 + lr) * 128 + lx) = outv[0];
        *(uint2*)(p + (size_t)(y0 + 8 + lr) * 128 + lx) = outv[1];
    }
    for (int off = 32; off; off >>= 1) ss += __shfl_down(ss, off);
    if ((t & 63) == 0) red[t >> 6] = ss;
    __syncthreads();
    if (t == 0) (sec == 0 ? sq : sk)[b * CC + c] = red[0] + red[1] + red[2] + red[3];
}

// ---- depthwise 3x3 on v planes, output directly in vT (MFMA-B) layout.
__global__ __launch_bounds__(256) void k_dw_v(
    const ushort* __restrict__ vb, const float* __restrict__ wdw,
    ushort* __restrict__ vT)
{
    __shared__ ushort obuf[4][8][128];
    const int cg = blockIdx.x, b = blockIdx.y, yq = blockIdx.z;
    const int t = threadIdx.x;
    const int c = t >> 5, lr = (t >> 3) & 3, xo = t & 7;
    const int ch = cg * 8 + c;
    const ushort* p = vb + ((size_t)b * CC + ch) * HW;
    const float* wc9 = wdw + (size_t)(2 * CC + ch) * 9;
    float wt[9];
    #pragma unroll
    for (int i = 0; i < 9; i++) wt[i] = wc9[i];
    ushort* tb = vT + (size_t)(b * 24 + cg) * HW * 8;
    const int x0 = xo * 16;

    for (int ic = 0; ic < 8; ic++) {
        const int y = yq * 32 + ic * 4 + lr;
        float a[16];
        #pragma unroll
        for (int j = 0; j < 16; j++) a[j] = 0.f;
        #pragma unroll
        for (int dy = 0; dy < 3; dy++) {
            int ry = y - 1 + dy;
            if (ry >= 0 && ry < 128) {
                const ushort* r = p + (size_t)ry * 128 + x0;
                float wv[18];
                uint4 v0 = *(const uint4*)r;
                uint4 v1 = *(const uint4*)(r + 8);
                unsigned uu[8] = {v0.x, v0.y, v0.z, v0.w, v1.x, v1.y, v1.z, v1.w};
                #pragma unroll
                for (int q = 0; q < 8; q++) {
                    union { unsigned u; float f; } lo, hi;
                    lo.u = uu[q] << 16;  hi.u = uu[q] & 0xFFFF0000u;
                    wv[1 + 2*q] = lo.f;  wv[2 + 2*q] = hi.f;
                }
                wv[0]  = x0 ? ubf(r[-1]) : 0.f;
                wv[17] = (x0 < 112) ? ubf(r[16]) : 0.f;
                float t0 = wt[dy*3], t1 = wt[dy*3+1], t2 = wt[dy*3+2];
                #pragma unroll
                for (int j = 0; j < 16; j++)
                    a[j] += t0 * wv[j] + t1 * wv[j+1] + t2 * wv[j+2];
            }
        }
        __syncthreads();   // prev gather done before overwrite
        ushort tmp[16];
        #pragma unroll
        for (int j = 0; j < 16; j++) tmp[j] = bfu(a[j]);
        *(int4*)&obuf[lr][c][x0]     = *(int4*)&tmp[0];
        *(int4*)&obuf[lr][c][x0 + 8] = *(int4*)&tmp[8];
        __syncthreads();
        #pragma unroll
        for (int rep = 0; rep < 2; rep++) {
            int u = t + rep * 256;
            int row = u >> 7, x = u & 127;
            int4 gi;
            ushort* g = (ushort*)&gi;
            #pragma unroll
            for (int cc = 0; cc < 8; cc++) g[cc] = obuf[row][cc][x];
            int yg = yq * 32 + ic * 4 + row;
            *(int4*)(tb + ((size_t)yg * 128 + x) * 8) = gi;
        }
    }
}

// ---- Gram via MFMA 16x16x32, strided global operands; 32 slabs for occupancy
__global__ __launch_bounds__(256) void k_gram(
    const ushort* __restrict__ qk, float* __restrict__ G)
{
    int slab = blockIdx.x, h = blockIdx.y, b = blockIdx.z;
    const int t = threadIdx.x, lane = t & 63, w = t >> 6;
    const ushort* qb = qk + ((size_t)b * CC + h * CHD) * HW;
    const ushort* kb = qk + ((size_t)(BB + b) * CC + h * CHD) * HW;
    const int ll = lane & 15, lh = lane >> 4;
    f4v acc[3][3];
    #pragma unroll
    for (int i = 0; i < 3; i++)
        #pragma unroll
        for (int j = 0; j < 3; j++)
            #pragma unroll
            for (int r = 0; r < 4; r++) acc[i][j][r] = 0.f;
    const int nbase = slab * 512 + w * 128 + lh * 8;
    #pragma unroll
    for (int s = 0; s < 4; s++) {
        const int n = nbase + s * 32;
        s8v aq[3], bk[3];
        #pragma unroll
        for (int mt = 0; mt < 3; mt++)
            aq[mt] = *(const s8v*)(qb + (size_t)(mt * 16 + ll) * HW + n);
        #pragma unroll
        for (int mt = 0; mt < 3; mt++)
            bk[mt] = *(const s8v*)(kb + (size_t)(mt * 16 + ll) * HW + n);
        #pragma unroll
        for (int i = 0; i < 3; i++)
            #pragma unroll
            for (int j = 0; j < 3; j++)
                acc[i][j] = __builtin_amdgcn_mfma_f32_16x16x32_bf16(aq[i], bk[j], acc[i][j], 0, 0, 0);
    }
    float* Gb = G + (size_t)(b * HEADS + h) * CHD * CHD;
    #pragma unroll
    for (int i = 0; i < 3; i++)
        #pragma unroll
        for (int j = 0; j < 3; j++)
            #pragma unroll
            for (int r = 0; r < 4; r++) {
                int cc = i * 16 + lh * 4 + r, d = j * 16 + ll;
                atomicAdd(&Gb[cc * CHD + d], acc[i][j][r]);
            }
}

// ---- attn = relu(G*temp/(|q||k|)); MPack[b][c/8][o][c&7] (bf16, A-frag order)
__global__ __launch_bounds__(256) void k_compose(
    const float* __restrict__ G, const float* __restrict__ sq, const float* __restrict__ sk,
    const float* __restrict__ temp, const float* __restrict__ wproj,
    ushort* __restrict__ Mbf)
{
    __shared__ float attnS[CHD * CHD];
    __shared__ float wS[CC * CHD];
    int h = blockIdx.x, b = blockIdx.y, t = threadIdx.x;
    float tv = temp[h];
    const float* Gb = G + (size_t)(b * HEADS + h) * CHD * CHD;
    const float* sqb = sq + b * CC + h * CHD;
    const float* skb = sk + b * CC + h * CHD;
    #pragma unroll
    for (int i = 0; i < 9; i++) {
        int idx = i * 256 + t;
        int c = idx / CHD, d = idx % CHD;
        float nq = fmaxf(sqrtf(sqb[c]), 1e-12f);
        float nk = fmaxf(sqrtf(skb[d]), 1e-12f);
        float v = Gb[idx] * tv / (nq * nk);
        attnS[idx] = fmaxf(v, 0.f);
    }
    #pragma unroll
    for (int i = 0; i < 36; i++) {
        int idx = i * 256 + t;
        wS[idx] = wproj[(idx / CHD) * CC + h * CHD + idx % CHD];
    }
    __syncthreads();
    ushort* Mb = Mbf + (size_t)b * CC * CC;
    #pragma unroll
    for (int i = 0; i < 36; i++) {
        int idx = i * 256 + t;
        int o = idx / CHD, d = idx % CHD;
        float s = 0.f;
        #pragma unroll 8
        for (int c2 = 0; c2 < CHD; c2++)
            s += wS[o * CHD + c2] * attnS[c2 * CHD + d];
        int cglob = h * CHD + d;          // contraction index
        Mb[(size_t)(cglob >> 3) * CC * 8 + o * 8 + (cglob & 7)] = bfu(s);
    }
}

extern "C" void kernel_launch(void* const* d_in, const int* in_sizes, int n_in,
                              void* d_out, int out_size, void* d_ws, size_t ws_size,
                              hipStream_t stream)
{
    const float* x      = (const float*)d_in[0];
    const float* w_qkv  = (const float*)d_in[1];
    const float* w_dw   = (const float*)d_in[2];
    const float* w_proj = (const float*)d_in[3];
    const float* temp   = (const float*)d_in[4];
    float* out = (float*)d_out;

    // d_out doubles as q_bf/k_bf planes (exactly out_size*4 bytes)
    ushort* qk = (ushort*)d_out;

    // ws layout (~97.1 MB): [xT(->vT)][v planes][G][sq][sk][wbf][Mbf]
    ushort* xT = (ushort*)d_ws;                        // 25,165,824 u16 (reused as vT)
    ushort* vb = xT + (size_t)BB * CC * HW;            // 25,165,824 u16
    float*  G  = (float*)(vb + (size_t)BB * CC * HW);  // 73,728 f
    float*  sq = G + (size_t)BB * HEADS * CHD * CHD;   // 1,536 f
    float*  sk = sq + (size_t)BB * CC;                 // 1,536 f
    ushort* wbf = (ushort*)(sk + (size_t)BB * CC);     // 110,592 u16
    ushort* Mbf = wbf + (size_t)C3 * CC;               // 294,912 u16

    // x -> xT (bf16, MFMA-B layout); folds in w-pack conversion + G zeroing
    k_trans<<<dim3(BB, 24, 16), 256, 0, stream>>>(x, xT, w_qkv, wbf, G);

    // fused qkv GEMM: q,k -> d_out planes, v -> vb planes
    gemm_mfma<0><<<dim3(3072), 256, 0, stream>>>(wbf, xT, qk, vb, nullptr);

    // depthwise 3x3 in place on q/k planes + exact sum-of-squares
    k_dw_bf<<<dim3(2 * NPLANE), 256, 0, stream>>>(qk, w_dw, sq, sk);

    // depthwise 3x3 on v, fused transpose -> vT (xT slot; xT dead after gemm0)
    k_dw_v<<<dim3(24, BB, 4), 256, 0, stream>>>(vb, w_dw, xT);

    // channel Gram per (b,head)
    k_gram<<<dim3(32, HEADS, BB), 256, 0, stream>>>(qk, G);

    // attn + fold output projection into per-batch M (bf16, fragment order)
    k_compose<<<dim3(HEADS, BB), 256, 0, stream>>>(G, sq, sk, temp, w_proj, Mbf);

    // out = M_b @ v_dw (fp32, overwrites q/k region of d_out)
    gemm_mfma<1><<<dim3(1024), 256, 0, stream>>>(Mbf, xT, nullptr, nullptr, out);
}